// Round 6
// baseline (64.169 us; speedup 1.0000x reference)
//
#include <hip/hip_runtime.h>

#define T_LEN 768
#define TC 32                 // timesteps per chunk
#define NCH (T_LEN / TC)      // 24 chunks
#define SA 36                 // input plane stride (16B-aligned rows)
#define SO 65                 // output plane stride

struct Params { const float* p[27]; };

__device__ __forceinline__ float ex2(float x){ float r; asm("v_exp_f32 %0, %1":"=v"(r):"v"(x)); return r; }
__device__ __forceinline__ float frcp(float x){ return __builtin_amdgcn_rcpf(x); }
__device__ __forceinline__ float dpp_xor1(float x){
    // lane <-> lane^1 swap, quad_perm [1,0,3,2]; pure VALU, no LDS
    return __int_as_float(__builtin_amdgcn_mov_dpp(__float_as_int(x),0xB1,0xF,0xF,true));
}
__device__ __forceinline__ float psig(float v, float k, float c){
    return frcp(1.0f + ex2(__builtin_fmaf(-k, v, c)));
}

// Single wave per block, 2 lanes per row (even = x, odd = y). Everything
// in-wave: loads, staging, sigmoids, serial chain, drain. No barriers.
//
// SHARE serial state (per lane): W = c2 - k2*v (exp2 argument), D = 1+2^W,
// em1 = D-1, r = sigma = 1/D. Per step (7-op carried chain):
//   nt = fma(-D, rs, 2) ; r = rs*nt            (1 Newton iter, extrapolated seed)
//   rp = dpp(r)                                 (partner sigma)
//   dl = fma(rp, h3, fma(r, h2, rr*h1))         (W-increment; h_i off-chain)
//   qq = fma(P2, dl, P1) ; p = fma(dl, qq, 1)   (2^dl, deg-2)
//   D' = fma(em1, p, 1)  ; em1' = em1*p         (parallel)
// Exact exp2+rcp re-anchor every chunk kills drift.
__global__ __launch_bounds__(64, 1) void cell_kernel(Params P, float* __restrict__ out) {
    __shared__ float lds_a[32][SA];
    __shared__ float lds_b[32][SA];
    __shared__ float lds_o[TC][SO];

    const int l  = (int)threadIdx.x;
    const int r0 = (int)blockIdx.x * 32;
    const bool isX = (l & 1) == 0;
    const int row = l >> 1;

    const float* __restrict__ inp = P.p[0];
    const float capx = P.p[1][0], capy = P.p[2][0];
    const float g_ax = P.p[3][0],  m_ax = P.p[4][0],  s_ax = P.p[5][0],  q_ax = P.p[6][0];
    const float g_by = P.p[7][0],  m_by = P.p[8][0],  s_by = P.p[9][0],  q_by = P.p[10][0];
    const float g_xx = P.p[11][0], m_xx = P.p[12][0], s_xx = P.p[13][0], q_xx = P.p[14][0];
    const float g_xy = P.p[15][0], m_xy = P.p[16][0], s_xy = P.p[17][0], q_xy = P.p[18][0];
    const float g_yx = P.p[19][0], m_yx = P.p[20][0], s_yx = P.p[21][0], q_yx = P.p[22][0];
    const float g_yy = P.p[23][0], m_yy = P.p[24][0], s_yy = P.p[25][0], q_yy = P.p[26][0];

    const float icx = 1.0f / capx, icy = 1.0f / capy;
    const float L2E = 1.44269504088896340736f;
    const float LN2 = 0.69314718056f;
    const float P1q = 0.69314718056f, P2q = 0.2402265070f;   // 2^d ~ 1+d(P1+d*P2)

    // input-synapse sigmoid (per lane: own channel's input)
    const float k1r = (isX ? s_ax : s_by) * L2E;
    const float c1r = k1r * (isX ? m_ax : m_by);
    // self sigmoid
    const float k2r = (isX ? s_xx : s_yy) * L2E;
    const float c2r = k2r * (isX ? m_xx : m_yy);
    // cross-OUT sigmoid (general path only)
    const float k3r = (isX ? s_xy : s_yx) * L2E;
    const float c3r = k3r * (isX ? m_xy : m_yx);
    const float icr = isX ? icx : icy;
    const float A1r = (isX ? g_ax * q_ax : g_by * q_by) * icr, G1r = (isX ? g_ax : g_by) * icr;
    const float A2r = (isX ? g_xx * q_xx : g_yy * q_yy) * icr, G2r = (isX ? g_xx : g_yy) * icr;
    const float A3r = (isX ? g_yx * q_yx : g_xy * q_xy) * icr, G3r = (isX ? g_yx : g_xy) * icr;

    // W-space constants: h_i = fma(-G_i, W, R_i), R_i = G_i*c2 - k2*A_i
    const float R1 = __builtin_fmaf(G1r, c2r, -k2r * A1r);
    const float R2 = __builtin_fmaf(G2r, c2r, -k2r * A2r);
    const float R3 = __builtin_fmaf(G3r, c2r, -k2r * A3r);
    const float mG1 = -G1r, mG2 = -G2r, mG3 = -G3r;
    const float nik2 = -1.0f / k2r, ofs = c2r / k2r;         // v recovery

    const bool share = (s_yx == s_yy) && (m_yx == m_yy) &&
                       (s_xy == s_xx) && (m_xy == m_xx) &&
                       (s_xx != 0.0f) && (s_yy != 0.0f);

    const float4* __restrict__ in4 = (const float4*)inp;     // row stride 384 f4

    float4 bufG[8];
    float raw[TC];   // next chunk: raw inputs, overwritten in place with sigmas
    float rr[TC];    // current chunk: input sigmas

    auto LOAD = [&](int c) {
        #pragma unroll
        for (int k = 0; k < 8; ++k) { int idx = l + 64*k; int r_ = idx >> 4, q = idx & 15;
            bufG[k] = in4[(size_t)(r0 + r_) * 384 + c * 16 + q]; }
    };
    auto STAGE = [&]() {          // deinterleave (a,b,a,b) -> a-plane / b-plane
        #pragma unroll
        for (int k = 0; k < 8; ++k) { int idx = l + 64*k; int r_ = idx >> 4, q = idx & 15;
            lds_a[r_][2*q]   = bufG[k].x;  lds_b[r_][2*q]   = bufG[k].y;
            lds_a[r_][2*q+1] = bufG[k].z;  lds_b[r_][2*q+1] = bufG[k].w; }
    };
    auto READRAW = [&]() {
        const float* pl = isX ? &lds_a[0][0] : &lds_b[0][0];
        #pragma unroll
        for (int j = 0; j < 8; ++j) {
            float4 v4 = *(const float4*)&pl[row * SA + 4*j];
            raw[4*j] = v4.x; raw[4*j+1] = v4.y; raw[4*j+2] = v4.z; raw[4*j+3] = v4.w;
        }
    };
    auto DRAIN = [&](int c) {     // coalesced: 256 f4 = 32 rows x 8 (x = even cols)
        #pragma unroll
        for (int k = 0; k < 4; ++k) { int f = l + 64*k; int r_ = f >> 3, pq = f & 7;
            float4 o;
            o.x = lds_o[4*pq + 0][2*r_];
            o.y = lds_o[4*pq + 1][2*r_];
            o.z = lds_o[4*pq + 2][2*r_];
            o.w = lds_o[4*pq + 3][2*r_];
            *(float4*)&out[(size_t)(r0 + r_) * T_LEN + c * TC + 4*pq] = o; }
    };

    // ---- prologue: chunk 0 sigmas, chunk 1 raw in flight ----
    LOAD(0); STAGE(); READRAW();
    #pragma unroll
    for (int t = 0; t < TC; ++t) rr[t] = psig(raw[t], k1r, c1r);
    LOAD(1);

    float W = c2r;                 // share state (v = 0)
    float v = 0.0f;                // general state

    for (int c = 0; c < NCH; ++c) {
        const bool hasN = (c + 1 < NCH);
        if (hasN) { STAGE(); READRAW(); }          // raw <- chunk c+1 inputs
        if (c + 2 < NCH) LOAD(c + 2);              // bufG <- chunk c+2 (in flight)

        if (share) {
            // exact re-anchor at chunk start
            float E  = ex2(W);
            float D  = 1.0f + E;
            float r  = frcp(D);
            float em1 = E;
            float h1 = __builtin_fmaf(mG1, W, R1);
            float h2 = __builtin_fmaf(mG2, W, R2);
            float h3 = __builtin_fmaf(mG3, W, R3);
            float cfac = 0.0f, dlp = 0.0f;
            #pragma unroll
            for (int t = 0; t < TC; ++t) {
                float rs = __builtin_fmaf(cfac, dlp, r);      // extrapolated seed
                float nt = __builtin_fmaf(-D, rs, 2.0f);      // (1)
                r        = rs * nt;                           // (2) sigma
                float rp = dpp_xor1(r);                       // (3) partner sigma
                float p1 = rr[t] * h1;                        //  off-chain
                float s2mW = __builtin_fmaf(r, h2, p1);       //  ||(3)
                float dl = __builtin_fmaf(rp, h3, s2mW);      // (4) W-increment
                float qq = __builtin_fmaf(P2q, dl, P1q);      // (5)
                float pp = __builtin_fmaf(dl, qq, 1.0f);      // (6) 2^dl
                float Dn = __builtin_fmaf(em1, pp, 1.0f);     // (7)
                em1 = em1 * pp;                               //  ||(7)
                W = W + dl;                                   //  off-chain
                D = Dn; dlp = dl;
                float t1 = __builtin_fmaf(-r, r, r);          // r(1-r)
                cfac = -LN2 * t1;                             // d(sigma)/dW
                h1 = __builtin_fmaf(mG1, W, R1);
                h2 = __builtin_fmaf(mG2, W, R2);
                h3 = __builtin_fmaf(mG3, W, R3);
                lds_o[t][l] = __builtin_fmaf(W, nik2, ofs);   // v (x in even lanes)
                raw[t] = psig(raw[t], k1r, c1r);              // next chunk sigma (slack)
            }
        } else {
            #pragma unroll
            for (int t = 0; t < TC; ++t) {
                float s2 = psig(v, k2r, c2r);
                float s3 = psig(v, k3r, c3r);
                float rp = dpp_xor1(s3);
                float u1 = __builtin_fmaf(-v, G1r, A1r);
                float u2 = __builtin_fmaf(-v, G2r, A2r);
                float u3 = __builtin_fmaf(-v, G3r, A3r);
                v = __builtin_fmaf(rp, u3,
                    __builtin_fmaf(s2, u2,
                    __builtin_fmaf(rr[t], u1, v)));
                lds_o[t][l] = v;
                raw[t] = psig(raw[t], k1r, c1r);
            }
        }

        DRAIN(c);
        #pragma unroll
        for (int t = 0; t < TC; ++t) rr[t] = raw[t];          // next chunk sigmas
    }
}

extern "C" void kernel_launch(void* const* d_in, const int* in_sizes, int n_in,
                              void* d_out, int out_size, void* d_ws, size_t ws_size,
                              hipStream_t stream) {
    (void)d_ws; (void)ws_size; (void)out_size; (void)n_in;
    Params P;
    for (int i = 0; i < 27; ++i) P.p[i] = (const float*)d_in[i];
    float* out = (float*)d_out;
    const int B = in_sizes[0] / (T_LEN * 2);   // 16384
    dim3 grid(B / 32);                         // 512 blocks x 64 threads (1 wave)
    cell_kernel<<<grid, dim3(64), 0, stream>>>(P, out);
}

// Round 7
// 44.713 us; speedup vs baseline: 1.4351x; 1.4351x over previous
//
#include <hip/hip_runtime.h>

#define T_LEN 768
#define TC 32                 // timesteps per chunk
#define NCH (T_LEN / TC)      // 24 chunks
#define RPB 32                // rows per block
#define R1S 36                // r1buf row stride (floats): 16B-aligned
#define OS  66                // lds_o stride

struct Params { const float* p[27]; };

__device__ __forceinline__ float ex2(float x){ float r; asm("v_exp_f32 %0, %1":"=v"(r):"v"(x)); return r; }
__device__ __forceinline__ float frcp(float x){ return __builtin_amdgcn_rcpf(x); }
__device__ __forceinline__ float dpp_xor1(float x){
    // lane <-> lane^1 swap, quad_perm [1,0,3,2]; pure VALU
    return __int_as_float(__builtin_amdgcn_mov_dpp(__float_as_int(x),0xB1,0xF,0xF,true));
}
__device__ __forceinline__ float psig(float v, float k, float c){
    return frcp(1.0f + ex2(__builtin_fmaf(-k, v, c)));
}

// Block = 128 threads: wave0 = serial consumer (2 lanes/row x 32 rows, all
// housekeeping off its issue stream), wave1 = producer (global loads, input
// sigmoids, output drains). One barrier per chunk, double-buffered LDS.
//
// Consumer SHARE state: W = c2 - k2*v (exp2 arg), D = 1+2^W, em1 = D-1,
// r = sigma = 1/D. Per step, 7-op carried cycle (NO transcendentals):
//   rs = fma(cfac, dlp, r)        extrapolated Newton seed
//   nt = fma(-D, rs, 2); r = rs*nt
//   rp = dpp(r)                   partner sigma
//   dl = fma(rp,h3, fma(r,h2, rr*h1))
//   qq = fma(P2,dl,P1); pp = fma(dl,qq,1)    2^dl (deg-2)
//   D' = fma(em1,pp,1); em1 *= pp
// Exact exp2+rcp re-anchor every chunk caps drift.
__global__ __launch_bounds__(128, 1) void cell_kernel(Params P, float* __restrict__ out) {
    __shared__ float r1buf[2][64][R1S];   // [buf][consumer-lane][t]
    __shared__ float lds_o[2][TC][OS];    // [buf][t][consumer-lane]

    const int tid = (int)threadIdx.x;
    const int r0  = (int)blockIdx.x * RPB;
    const bool isProd = tid >= 64;
    const int l = tid & 63;

    const float* __restrict__ inp = P.p[0];
    const float capx = P.p[1][0], capy = P.p[2][0];
    const float g_ax = P.p[3][0],  m_ax = P.p[4][0],  s_ax = P.p[5][0],  q_ax = P.p[6][0];
    const float g_by = P.p[7][0],  m_by = P.p[8][0],  s_by = P.p[9][0],  q_by = P.p[10][0];
    const float g_xx = P.p[11][0], m_xx = P.p[12][0], s_xx = P.p[13][0], q_xx = P.p[14][0];
    const float g_xy = P.p[15][0], m_xy = P.p[16][0], s_xy = P.p[17][0], q_xy = P.p[18][0];
    const float g_yx = P.p[19][0], m_yx = P.p[20][0], s_yx = P.p[21][0], q_yx = P.p[22][0];
    const float g_yy = P.p[23][0], m_yy = P.p[24][0], s_yy = P.p[25][0], q_yy = P.p[26][0];

    const float icx = 1.0f / capx, icy = 1.0f / capy;
    const float L2E = 1.44269504088896340736f;
    const float LN2 = 0.69314718056f;
    const float P1q = 0.69314718056f, P2q = 0.2402265070f;   // 2^d ~ 1 + d(P1 + d*P2)

    // producer: input-synapse sigmoids
    const float k1x = s_ax * L2E, c1x = k1x * m_ax;
    const float k1y = s_by * L2E, c1y = k1y * m_by;

    // consumer role constants (even lane = x, odd = y)
    const bool isX = (l & 1) == 0;
    const float k2r = (isX ? s_xx : s_yy) * L2E;
    const float c2r = k2r * (isX ? m_xx : m_yy);
    const float k3r = (isX ? s_xy : s_yx) * L2E;             // cross-OUT (general path)
    const float c3r = k3r * (isX ? m_xy : m_yx);
    const float icr = isX ? icx : icy;
    const float A1r = (isX ? g_ax * q_ax : g_by * q_by) * icr, G1r = (isX ? g_ax : g_by) * icr;
    const float A2r = (isX ? g_xx * q_xx : g_yy * q_yy) * icr, G2r = (isX ? g_xx : g_yy) * icr;
    const float A3r = (isX ? g_yx * q_yx : g_xy * q_xy) * icr, G3r = (isX ? g_yx : g_xy) * icr;

    // W-space constants: h_i = fma(-G_i, W, R_i), R_i = G_i*c2 - k2*A_i
    const float R1 = __builtin_fmaf(G1r, c2r, -k2r * A1r);
    const float R2 = __builtin_fmaf(G2r, c2r, -k2r * A2r);
    const float R3 = __builtin_fmaf(G3r, c2r, -k2r * A3r);
    const float mG1 = -G1r, mG2 = -G2r, mG3 = -G3r;
    const float nik2 = -1.0f / k2r, ofs = c2r / k2r;         // v recovery

    const bool share = (s_yx == s_yy) && (m_yx == m_yy) &&
                       (s_xy == s_xx) && (m_xy == m_xx) &&
                       (s_xx != 0.0f) && (s_yy != 0.0f);

    const float4* __restrict__ in4 = (const float4*)inp;     // row stride 384 f4

    // ---- consumer state ----
    float W = c2r;            // share path (v = 0)
    float v = 0.0f;           // general path

    // ---- prologue: producer fills r1buf[0] ----
    if (isProd) {
        float4 pin[8];
        #pragma unroll
        for (int k = 0; k < 8; ++k) { int idx = l + 64*k; int rr_ = idx >> 4, q = idx & 15;
            pin[k] = in4[(size_t)(r0 + rr_) * 384 + q]; }
        #pragma unroll
        for (int k = 0; k < 8; ++k) { int idx = l + 64*k; int rr_ = idx >> 4, q = idx & 15;
            float* rA = &r1buf[0][2*rr_][0]; float* rB = &r1buf[0][2*rr_ + 1][0];
            rA[2*q]     = psig(pin[k].x, k1x, c1x);
            rB[2*q]     = psig(pin[k].y, k1y, c1y);
            rA[2*q + 1] = psig(pin[k].z, k1x, c1x);
            rB[2*q + 1] = psig(pin[k].w, k1y, c1y); }
    }
    __syncthreads();

    for (int c = 0; c < NCH; ++c) {
        if (isProd) {
            float4 pin[8];
            if (c + 1 < NCH) {                       // issue next chunk's loads
                #pragma unroll
                for (int k = 0; k < 8; ++k) { int idx = l + 64*k; int rr_ = idx >> 4, q = idx & 15;
                    pin[k] = in4[(size_t)(r0 + rr_) * 384 + (c + 1) * 16 + q]; }
            }
            if (c >= 1) {                            // drain chunk c-1
                const int buf = (c - 1) & 1;
                #pragma unroll
                for (int k = 0; k < 4; ++k) { int f = l + 64*k; int rr_ = f >> 3, p = f & 7;
                    float4 o;
                    o.x = lds_o[buf][4*p + 0][2*rr_];
                    o.y = lds_o[buf][4*p + 1][2*rr_];
                    o.z = lds_o[buf][4*p + 2][2*rr_];
                    o.w = lds_o[buf][4*p + 3][2*rr_];
                    *(float4*)&out[(size_t)(r0 + rr_) * T_LEN + (c - 1) * TC + 4*p] = o; }
            }
            if (c + 1 < NCH) {                       // sigmoids for chunk c+1
                const int buf = (c + 1) & 1;
                #pragma unroll
                for (int k = 0; k < 8; ++k) { int idx = l + 64*k; int rr_ = idx >> 4, q = idx & 15;
                    float* rA = &r1buf[buf][2*rr_][0]; float* rB = &r1buf[buf][2*rr_ + 1][0];
                    rA[2*q]     = psig(pin[k].x, k1x, c1x);
                    rB[2*q]     = psig(pin[k].y, k1y, c1y);
                    rA[2*q + 1] = psig(pin[k].z, k1x, c1x);
                    rB[2*q + 1] = psig(pin[k].w, k1y, c1y); }
            }
        } else {
            const int buf = c & 1;
            float rr[TC];                            // this chunk's input sigmas
            #pragma unroll
            for (int j = 0; j < 8; ++j) {
                float4 v4 = *(const float4*)&r1buf[buf][l][4*j];
                rr[4*j] = v4.x; rr[4*j+1] = v4.y; rr[4*j+2] = v4.z; rr[4*j+3] = v4.w;
            }
            if (share) {
                // exact re-anchor at chunk start (only trans in steady state)
                float E   = ex2(W);
                float D   = 1.0f + E;
                float r   = frcp(D);
                float em1 = E;
                float h1 = __builtin_fmaf(mG1, W, R1);
                float h2 = __builtin_fmaf(mG2, W, R2);
                float h3 = __builtin_fmaf(mG3, W, R3);
                float cfac = 0.0f, dlp = 0.0f;
                #pragma unroll
                for (int t = 0; t < TC; ++t) {
                    float rs = __builtin_fmaf(cfac, dlp, r);   // extrapolated seed
                    float nt = __builtin_fmaf(-D, rs, 2.0f);   // Newton
                    r        = rs * nt;                        // sigma
                    float rp = dpp_xor1(r);                    // partner sigma
                    float p1   = rr[t] * h1;                   // off-chain
                    float s2mW = __builtin_fmaf(r, h2, p1);
                    float dl   = __builtin_fmaf(rp, h3, s2mW); // W-increment
                    float qq = __builtin_fmaf(P2q, dl, P1q);
                    float pp = __builtin_fmaf(dl, qq, 1.0f);   // 2^dl
                    float Dn = __builtin_fmaf(em1, pp, 1.0f);
                    em1 = em1 * pp;
                    W = W + dl;
                    D = Dn; dlp = dl;
                    float t1 = __builtin_fmaf(-r, r, r);       // r(1-r)
                    cfac = -LN2 * t1;                          // d sigma / dW
                    h1 = __builtin_fmaf(mG1, W, R1);
                    h2 = __builtin_fmaf(mG2, W, R2);
                    h3 = __builtin_fmaf(mG3, W, R3);
                    lds_o[buf][t][l] = __builtin_fmaf(W, nik2, ofs);  // v
                }
            } else {
                #pragma unroll
                for (int t = 0; t < TC; ++t) {
                    float s2 = psig(v, k2r, c2r);
                    float s3 = psig(v, k3r, c3r);
                    float rp = dpp_xor1(s3);
                    float u1 = __builtin_fmaf(-v, G1r, A1r);
                    float u2 = __builtin_fmaf(-v, G2r, A2r);
                    float u3 = __builtin_fmaf(-v, G3r, A3r);
                    v = __builtin_fmaf(rp, u3,
                        __builtin_fmaf(s2, u2,
                        __builtin_fmaf(rr[t], u1, v)));
                    lds_o[buf][t][l] = v;
                }
            }
        }
        __syncthreads();
    }

    // final drain: chunk NCH-1
    if (isProd) {
        const int buf = (NCH - 1) & 1;
        #pragma unroll
        for (int k = 0; k < 4; ++k) { int f = l + 64*k; int rr_ = f >> 3, p = f & 7;
            float4 o;
            o.x = lds_o[buf][4*p + 0][2*rr_];
            o.y = lds_o[buf][4*p + 1][2*rr_];
            o.z = lds_o[buf][4*p + 2][2*rr_];
            o.w = lds_o[buf][4*p + 3][2*rr_];
            *(float4*)&out[(size_t)(r0 + rr_) * T_LEN + (NCH - 1) * TC + 4*p] = o; }
    }
}

extern "C" void kernel_launch(void* const* d_in, const int* in_sizes, int n_in,
                              void* d_out, int out_size, void* d_ws, size_t ws_size,
                              hipStream_t stream) {
    (void)d_ws; (void)ws_size; (void)out_size; (void)n_in;
    Params P;
    for (int i = 0; i < 27; ++i) P.p[i] = (const float*)d_in[i];
    float* out = (float*)d_out;
    const int B = in_sizes[0] / (T_LEN * 2);   // 16384
    dim3 grid(B / RPB);                        // 512 blocks x 128 threads (2 waves)
    cell_kernel<<<grid, dim3(128), 0, stream>>>(P, out);
}

// Round 8
// 38.393 us; speedup vs baseline: 1.6713x; 1.1646x over previous
//
#include <hip/hip_runtime.h>

#define T_LEN 768
#define TC 32                 // timesteps per chunk
#define NCH (T_LEN / TC)      // 24 chunks
#define RPB 32                // rows per block
#define R1S 36                // r1buf row stride (floats): 16B-aligned
#define OS  66                // lds_o stride

struct Params { const float* p[27]; };

__device__ __forceinline__ float ex2(float x){ float r; asm("v_exp_f32 %0, %1":"=v"(r):"v"(x)); return r; }
__device__ __forceinline__ float frcp(float x){ return __builtin_amdgcn_rcpf(x); }
__device__ __forceinline__ float dpp_xor1(float x){
    // lane <-> lane^1 swap, quad_perm [1,0,3,2]; pure VALU
    return __int_as_float(__builtin_amdgcn_mov_dpp(__float_as_int(x),0xB1,0xF,0xF,true));
}
__device__ __forceinline__ float psig(float v, float k, float c){
    return frcp(1.0f + ex2(__builtin_fmaf(-k, v, c)));
}

// Block = 128 threads: wave0 = serial consumer (2 lanes/row x 32 rows),
// wave1 = producer (global loads, input sigmoids, output drains + h2->v map).
//
// Consumer SHARE state (per lane): sigma (own sigmoid), h1,h2,h3 (synapse
// drives, linear in W and updated incrementally), cfac = -ln2*sg*(1-sg),
// hd2 = (1/2)sigma'' (refreshed every 4 steps), dl2p = lagged dl^2.
// Per step (~13 inst, 3-op carried cycle sg -> dpp -> dl -> sg'):
//   rp  = dpp(sg)
//   dl  = fma(rp, h3, fma(sg, h2, p1))        p1 = rr[t]*h1 (prev step)
//   sg' = fma(cfac, dl, fma(hd2, dl2p, sg))
//   h1..h3 += mG*dl ; p1 = rr[t+1]*h1 ; t1/cfac ; store h2
// Exact exp2+rcp re-anchor every chunk caps drift (W recovered from h2).
__global__ __launch_bounds__(128, 1) void cell_kernel(Params P, float* __restrict__ out) {
    __shared__ float r1buf[2][64][R1S];   // [buf][consumer-lane][t]
    __shared__ float lds_o[2][TC][OS];    // [buf][t][consumer-lane]

    const int tid = (int)threadIdx.x;
    const int r0  = (int)blockIdx.x * RPB;
    const bool isProd = tid >= 64;
    const int l = tid & 63;

    const float* __restrict__ inp = P.p[0];
    const float capx = P.p[1][0], capy = P.p[2][0];
    const float g_ax = P.p[3][0],  m_ax = P.p[4][0],  s_ax = P.p[5][0],  q_ax = P.p[6][0];
    const float g_by = P.p[7][0],  m_by = P.p[8][0],  s_by = P.p[9][0],  q_by = P.p[10][0];
    const float g_xx = P.p[11][0], m_xx = P.p[12][0], s_xx = P.p[13][0], q_xx = P.p[14][0];
    const float g_xy = P.p[15][0], m_xy = P.p[16][0], s_xy = P.p[17][0], q_xy = P.p[18][0];
    const float g_yx = P.p[19][0], m_yx = P.p[20][0], s_yx = P.p[21][0], q_yx = P.p[22][0];
    const float g_yy = P.p[23][0], m_yy = P.p[24][0], s_yy = P.p[25][0], q_yy = P.p[26][0];

    const float icx = 1.0f / capx, icy = 1.0f / capy;
    const float L2E  = 1.44269504088896340736f;
    const float LN2  = 0.69314718056f;
    const float mLN2 = -0.69314718056f;
    const float mHLN2 = -0.34657359028f;      // -ln2/2

    // producer: input-synapse sigmoids
    const float k1x = s_ax * L2E, c1x = k1x * m_ax;
    const float k1y = s_by * L2E, c1y = k1y * m_by;

    // consumer role constants (even lane = x, odd = y)
    const bool isX = (l & 1) == 0;
    const float k2r = (isX ? s_xx : s_yy) * L2E;
    const float c2r = k2r * (isX ? m_xx : m_yy);
    const float k3r = (isX ? s_xy : s_yx) * L2E;             // cross-OUT (general path)
    const float c3r = k3r * (isX ? m_xy : m_yx);
    const float icr = isX ? icx : icy;
    const float A1r = (isX ? g_ax * q_ax : g_by * q_by) * icr, G1r = (isX ? g_ax : g_by) * icr;
    const float A2r = (isX ? g_xx * q_xx : g_yy * q_yy) * icr, G2r = (isX ? g_xx : g_yy) * icr;
    const float A3r = (isX ? g_yx * q_yx : g_xy * q_xy) * icr, G3r = (isX ? g_yx : g_xy) * icr;

    // W-space constants: h_i = fma(mG_i, W, R_i), R_i = G_i*c2 - k2*A_i
    const float R1 = __builtin_fmaf(G1r, c2r, -k2r * A1r);
    const float R2 = __builtin_fmaf(G2r, c2r, -k2r * A2r);
    const float R3 = __builtin_fmaf(G3r, c2r, -k2r * A3r);
    const float mG1 = -G1r, mG2 = -G2r, mG3 = -G3r;
    const float inv_mG2 = 1.0f / mG2;                        // setup-only divide

    const bool share = (s_yx == s_yy) && (m_yx == m_yy) &&
                       (s_xy == s_xx) && (m_xy == m_xx) &&
                       (s_xx != 0.0f) && (s_yy != 0.0f) &&
                       (g_xx != 0.0f) && (g_yy != 0.0f);

    // producer drain conversion: v = fma(stored, cv1, cv0)
    // share: stored = h2(x-chan); v = c2x/k2x - R2x/(G2x*k2x) + h2/(G2x*k2x)
    const float k2xp = s_xx * L2E, c2xp = k2xp * m_xx;
    const float G2xp = g_xx * icx;
    const float A2xp = g_xx * q_xx * icx;
    const float R2xp = __builtin_fmaf(G2xp, c2xp, -k2xp * A2xp);
    const float cv1 = share ? 1.0f / (G2xp * k2xp) : 1.0f;
    const float cv0 = share ? (c2xp / k2xp - R2xp * (1.0f / (G2xp * k2xp))) : 0.0f;

    const float4* __restrict__ in4 = (const float4*)inp;     // row stride 384 f4

    // ---- consumer state init (v = 0 -> W = c2) ----
    float h1 = __builtin_fmaf(mG1, c2r, R1);
    float h2 = __builtin_fmaf(mG2, c2r, R2);
    float h3 = __builtin_fmaf(mG3, c2r, R3);
    float v = 0.0f;           // general path

    // ---- prologue: producer fills r1buf[0] ----
    if (isProd) {
        float4 pin[8];
        #pragma unroll
        for (int k = 0; k < 8; ++k) { int idx = l + 64*k; int rr_ = idx >> 4, q = idx & 15;
            pin[k] = in4[(size_t)(r0 + rr_) * 384 + q]; }
        #pragma unroll
        for (int k = 0; k < 8; ++k) { int idx = l + 64*k; int rr_ = idx >> 4, q = idx & 15;
            float* rA = &r1buf[0][2*rr_][0]; float* rB = &r1buf[0][2*rr_ + 1][0];
            rA[2*q]     = psig(pin[k].x, k1x, c1x);
            rB[2*q]     = psig(pin[k].y, k1y, c1y);
            rA[2*q + 1] = psig(pin[k].z, k1x, c1x);
            rB[2*q + 1] = psig(pin[k].w, k1y, c1y); }
    }
    __syncthreads();

    for (int c = 0; c < NCH; ++c) {
        if (isProd) {
            float4 pin[8];
            if (c + 1 < NCH) {                       // issue next chunk's loads
                #pragma unroll
                for (int k = 0; k < 8; ++k) { int idx = l + 64*k; int rr_ = idx >> 4, q = idx & 15;
                    pin[k] = in4[(size_t)(r0 + rr_) * 384 + (c + 1) * 16 + q]; }
            }
            if (c >= 1) {                            // drain chunk c-1 (+ h2 -> v)
                const int buf = (c - 1) & 1;
                #pragma unroll
                for (int k = 0; k < 4; ++k) { int f = l + 64*k; int rr_ = f >> 3, p = f & 7;
                    float4 o;
                    o.x = __builtin_fmaf(lds_o[buf][4*p + 0][2*rr_], cv1, cv0);
                    o.y = __builtin_fmaf(lds_o[buf][4*p + 1][2*rr_], cv1, cv0);
                    o.z = __builtin_fmaf(lds_o[buf][4*p + 2][2*rr_], cv1, cv0);
                    o.w = __builtin_fmaf(lds_o[buf][4*p + 3][2*rr_], cv1, cv0);
                    *(float4*)&out[(size_t)(r0 + rr_) * T_LEN + (c - 1) * TC + 4*p] = o; }
            }
            if (c + 1 < NCH) {                       // sigmoids for chunk c+1
                const int buf = (c + 1) & 1;
                #pragma unroll
                for (int k = 0; k < 8; ++k) { int idx = l + 64*k; int rr_ = idx >> 4, q = idx & 15;
                    float* rA = &r1buf[buf][2*rr_][0]; float* rB = &r1buf[buf][2*rr_ + 1][0];
                    rA[2*q]     = psig(pin[k].x, k1x, c1x);
                    rB[2*q]     = psig(pin[k].y, k1y, c1y);
                    rA[2*q + 1] = psig(pin[k].z, k1x, c1x);
                    rB[2*q + 1] = psig(pin[k].w, k1y, c1y); }
            }
        } else {
            const int buf = c & 1;
            float rr[TC];                            // this chunk's input sigmas
            #pragma unroll
            for (int j = 0; j < 8; ++j) {
                float4 v4 = *(const float4*)&r1buf[buf][l][4*j];
                rr[4*j] = v4.x; rr[4*j+1] = v4.y; rr[4*j+2] = v4.z; rr[4*j+3] = v4.w;
            }
            if (share) {
                // ---- exact anchor: recover W from h2 (exactly linear) ----
                float Wr  = (h2 - R2) * inv_mG2;
                float E   = ex2(Wr);
                float sg  = frcp(1.0f + E);                  // sigma
                float t1  = __builtin_fmaf(-sg, sg, sg);     // sg(1-sg)
                float cfac = mLN2 * t1;                      // d sigma / dW
                float w2  = __builtin_fmaf(LN2, sg, mHLN2);
                float hd2 = cfac * w2;                       // (1/2) sigma''
                float dl2p = 0.0f;
                float p1 = rr[0] * h1;
                #pragma unroll
                for (int t = 0; t < TC; ++t) {
                    float rp   = dpp_xor1(sg);               // partner sigma
                    float s2mW = __builtin_fmaf(sg, h2, p1);
                    float dl   = __builtin_fmaf(rp, h3, s2mW);   // W-increment
                    float inner = __builtin_fmaf(hd2, dl2p, sg); // 2nd order (lagged)
                    float sgn  = __builtin_fmaf(cfac, dl, inner);
                    dl2p = dl * dl;
                    h1 = __builtin_fmaf(mG1, dl, h1);
                    h2 = __builtin_fmaf(mG2, dl, h2);
                    h3 = __builtin_fmaf(mG3, dl, h3);
                    if (t + 1 < TC) p1 = rr[t + 1] * h1;
                    t1   = __builtin_fmaf(-sgn, sgn, sgn);
                    cfac = mLN2 * t1;
                    if ((t & 3) == 3) {                      // refresh hd2 (slow-varying)
                        w2  = __builtin_fmaf(LN2, sgn, mHLN2);
                        hd2 = cfac * w2;
                    }
                    lds_o[buf][t][l] = h2;                   // output proxy (affine in v)
                    sg = sgn;
                }
            } else {
                #pragma unroll
                for (int t = 0; t < TC; ++t) {
                    float s2 = psig(v, k2r, c2r);
                    float s3 = psig(v, k3r, c3r);
                    float rp = dpp_xor1(s3);
                    float u1 = __builtin_fmaf(-v, G1r, A1r);
                    float u2 = __builtin_fmaf(-v, G2r, A2r);
                    float u3 = __builtin_fmaf(-v, G3r, A3r);
                    v = __builtin_fmaf(rp, u3,
                        __builtin_fmaf(s2, u2,
                        __builtin_fmaf(rr[t], u1, v)));
                    lds_o[buf][t][l] = v;                    // cv = (1,0): stored as-is
                }
            }
        }
        __syncthreads();
    }

    // final drain: chunk NCH-1
    if (isProd) {
        const int buf = (NCH - 1) & 1;
        #pragma unroll
        for (int k = 0; k < 4; ++k) { int f = l + 64*k; int rr_ = f >> 3, p = f & 7;
            float4 o;
            o.x = __builtin_fmaf(lds_o[buf][4*p + 0][2*rr_], cv1, cv0);
            o.y = __builtin_fmaf(lds_o[buf][4*p + 1][2*rr_], cv1, cv0);
            o.z = __builtin_fmaf(lds_o[buf][4*p + 2][2*rr_], cv1, cv0);
            o.w = __builtin_fmaf(lds_o[buf][4*p + 3][2*rr_], cv1, cv0);
            *(float4*)&out[(size_t)(r0 + rr_) * T_LEN + (NCH - 1) * TC + 4*p] = o; }
    }
}

extern "C" void kernel_launch(void* const* d_in, const int* in_sizes, int n_in,
                              void* d_out, int out_size, void* d_ws, size_t ws_size,
                              hipStream_t stream) {
    (void)d_ws; (void)ws_size; (void)out_size; (void)n_in;
    Params P;
    for (int i = 0; i < 27; ++i) P.p[i] = (const float*)d_in[i];
    float* out = (float*)d_out;
    const int B = in_sizes[0] / (T_LEN * 2);   // 16384
    dim3 grid(B / RPB);                        // 512 blocks x 128 threads (2 waves)
    cell_kernel<<<grid, dim3(128), 0, stream>>>(P, out);
}